// Round 1
// baseline (89.683 us; speedup 1.0000x reference)
//
#include <hip/hip_runtime.h>
#include <hip/hip_bf16.h>
#include <math.h>
#include <climits>

#define BLOCK 256
#define CAP 4992                 // LDS floats per block: 19968 B -> 8 blocks/CU
#define LARGE_NEG (-1.0e9f)
#define SCORE_EPS 1e-6f
#define RANDP 0.1f
#define PROB_EPS 1e-12f
#define F32EPS 1.1920928955078125e-7f   // torch.finfo(float32).eps

// ---------- block reduction helpers (256 threads = 4 waves of 64) ----------
__device__ __forceinline__ float block_max_f(float v, float* redf) {
#pragma unroll
  for (int o = 32; o >= 1; o >>= 1) v = fmaxf(v, __shfl_xor(v, o));
  if ((threadIdx.x & 63) == 0) redf[threadIdx.x >> 6] = v;
  __syncthreads();
  float r = fmaxf(fmaxf(redf[0], redf[1]), fmaxf(redf[2], redf[3]));
  __syncthreads();
  return r;
}

__device__ __forceinline__ float block_sum_f(float v, float* redf) {
#pragma unroll
  for (int o = 32; o >= 1; o >>= 1) v += __shfl_xor(v, o);
  if ((threadIdx.x & 63) == 0) redf[threadIdx.x >> 6] = v;
  __syncthreads();
  float r = (redf[0] + redf[1]) + (redf[2] + redf[3]);
  __syncthreads();
  return r;
}

// ---------- kernel 0: detect valid_edges storage format -------------------
// byte-bool (~90% nonzero bytes) vs int32 0/1 (~22.5%) vs f32 0/1 (~45%).
// flag=1 -> 1 byte per element; flag=0 -> 4 bytes per element (nonzero test
// on the 32-bit word is correct for both int 0/1 and float 0.0/1.0).
__global__ void gfn_detect(const unsigned int* __restrict__ vwords, int nwords,
                           int nbytes, int* __restrict__ flag) {
  int c = 0;
  for (int i = threadIdx.x; i < nwords; i += BLOCK) {
    unsigned int w = vwords[i];
    c += ((w & 0x000000FFu) != 0) + ((w & 0x0000FF00u) != 0) +
         ((w & 0x00FF0000u) != 0) + ((w & 0xFF000000u) != 0);
  }
#pragma unroll
  for (int o = 32; o >= 1; o >>= 1) c += __shfl_xor(c, o);
  __shared__ int part[4];
  if ((threadIdx.x & 63) == 0) part[threadIdx.x >> 6] = c;
  __syncthreads();
  if (threadIdx.x == 0) {
    int t = part[0] + part[1] + part[2] + part[3];
    flag[0] = (2 * t > nbytes) ? 1 : 0;
  }
}

// ---------- kernel 1: segment pointers via binary search (batch is sorted) -
__global__ void gfn_ptr(const int* __restrict__ batch, int E, int G,
                        int* __restrict__ ptr) {
  int g = blockIdx.x * blockDim.x + threadIdx.x;
  if (g > G) return;
  int lo = 0, hi = E;
  while (lo < hi) {
    int mid = (lo + hi) >> 1;
    if (batch[mid] < g) lo = mid + 1; else hi = mid;
  }
  ptr[g] = lo;   // first edge with batch >= g; segment g = [ptr[g], ptr[g+1])
}

// ---------- kernel 2: one workgroup per graph, full fused pipeline --------
__global__ void gfn_main(const float* __restrict__ scores,
                         const float* __restrict__ resid,
                         const float* __restrict__ stop_resid,
                         const void* __restrict__ validp,
                         const int* __restrict__ ptr,
                         const int* __restrict__ flag,
                         float* __restrict__ out, int E, int G) {
  __shared__ float sdata[CAP];
  __shared__ float redf[4];
  __shared__ int redi[4];

  const int g = blockIdx.x;
  const int start = ptr[g];
  const int end = ptr[g + 1];
  const int n = end - start;
  const bool useLds = (n <= CAP);          // always true for this data; safe fallback otherwise
  const bool byteFmt = (flag[0] != 0);
  const unsigned char* vb = (const unsigned char*)validp;
  const int* vi = (const int*)validp;

  auto load_l = [&](int e) -> float {      // masked base logit
    float s = scores[e];
    int v = byteFmt ? (int)vb[e] : vi[e];
    return v ? __logf(fmaxf(s, SCORE_EPS)) : LARGE_NEG;
  };

  // ---- stage 1: base distribution (stop logit = 0, temp = 1) ----
  float m1 = LARGE_NEG, vc = 0.f;
  for (int i = threadIdx.x; i < n; i += BLOCK) {
    float l = load_l(start + i);
    if (useLds) sdata[i] = l;
    m1 = fmaxf(m1, l);
    if (l != LARGE_NEG) vc += 1.f;         // valid count
  }
  m1 = block_max_f(m1, redf);              // == LARGE_NEG if n==0 or none valid (matches ref)
  vc = block_sum_f(vc, redf);
  const float mj1 = fmaxf(m1, 0.f);
  float s1 = 0.f;
  for (int i = threadIdx.x; i < n; i += BLOCK) {
    float l = useLds ? sdata[i] : load_l(start + i);
    s1 += __expf(l - mj1);                 // invalid: exp(-1e9 - mj) == 0 exactly
  }
  s1 = block_sum_f(s1, redf);
  const float ld1 = mj1 + __logf(s1 + __expf(-mj1) + F32EPS);

  // ---- stage 2: combined = base_log + residual, renormalize (temp = 1) ----
  float m2 = LARGE_NEG;
  for (int i = threadIdx.x; i < n; i += BLOCK) {
    float l = useLds ? sdata[i] : load_l(start + i);
    float r = resid[start + i];
    float c = (l != LARGE_NEG) ? (l - ld1 + r) : LARGE_NEG;
    if (useLds) sdata[i] = c;              // overwrite own slots
    m2 = fmaxf(m2, c);
  }
  m2 = block_max_f(m2, redf);
  const float ss2 = stop_resid[g] - ld1;   // (0 - ld1) + stop_residual
  const float mj2 = fmaxf(m2, ss2);
  float s2 = 0.f;
  for (int i = threadIdx.x; i < n; i += BLOCK) {
    float c;
    if (useLds) c = sdata[i];
    else {
      float l = load_l(start + i);
      c = (l != LARGE_NEG) ? (l - ld1 + resid[start + i]) : LARGE_NEG;
    }
    s2 += __expf(c - mj2);
  }
  s2 = block_sum_f(s2, redf);
  const float ld2 = mj2 + __logf(s2 + __expf(ss2 - mj2) + F32EPS);
  const float clean_stop = ss2 - ld2;
  const float total = fmaxf(vc + 1.f, 1.f);
  const float invt = 1.f / total;

  // ---- stage 3: write clean_log_edge, mixed-sample argmax, outputs ----
  float bv = -INFINITY;                    // jax segment_max identity
  int bi = INT_MAX;                        // jax segment_min identity
  for (int i = threadIdx.x; i < n; i += BLOCK) {
    int e = start + i;
    float c;
    if (useLds) c = sdata[i];
    else {
      float l = load_l(e);
      c = (l != LARGE_NEG) ? (l - ld1 + resid[e]) : LARGE_NEG;
    }
    bool v = (c != LARGE_NEG);
    float clean = c - ld2;
    out[e] = v ? clean : LARGE_NEG;        // output 0
    float ls;
    if (v) {
      float p = (1.f - RANDP) * __expf(clean) + RANDP * invt;
      ls = __logf(fmaxf(p, PROB_EPS));
    } else ls = LARGE_NEG;
    if (ls > bv || (ls == bv && e < bi)) { bv = ls; bi = e; }   // min idx on ties
  }
#pragma unroll
  for (int o = 32; o >= 1; o >>= 1) {
    float v2 = __shfl_xor(bv, o);
    int i2 = __shfl_xor(bi, o);
    if (v2 > bv || (v2 == bv && i2 < bi)) { bv = v2; bi = i2; }
  }
  if ((threadIdx.x & 63) == 0) { redf[threadIdx.x >> 6] = bv; redi[threadIdx.x >> 6] = bi; }
  __syncthreads();
  if (threadIdx.x == 0) {
    bv = redf[0]; bi = redi[0];
    for (int w = 1; w < 4; ++w) {
      float v2 = redf[w]; int i2 = redi[w];
      if (v2 > bv || (v2 == bv && i2 < bi)) { bv = v2; bi = i2; }
    }
    float ssp = (1.f - RANDP) * __expf(clean_stop) + RANDP * invt;
    float lss = __logf(fmaxf(ssp, PROB_EPS));
    bool take_stop = (lss >= bv);
    float action = take_stop ? (float)end : (float)bi;   // stop idx = ptr[g+1]
    float lpf;
    if (take_stop) {
      lpf = clean_stop;
    } else {
      // !take_stop => bi is a valid edge inside [start, end)
      int cb = bi < (E - 1) ? bi : (E - 1);
      float chosen;
      if (useLds) {
        chosen = sdata[cb - start] - ld2;
      } else {
        float l = load_l(cb);
        float c = (l != LARGE_NEG) ? (l - ld1 + resid[cb]) : LARGE_NEG;
        chosen = c - ld2;
      }
      lpf = chosen;
    }
    out[E + g]         = clean_stop;       // output 1
    out[E + G + g]     = action;           // output 2 (int stored as exact f32)
    out[E + 2 * G + g] = lpf;              // output 3
  }
}

extern "C" void kernel_launch(void* const* d_in, const int* in_sizes, int n_in,
                              void* d_out, int out_size, void* d_ws, size_t ws_size,
                              hipStream_t stream) {
  const float* scores     = (const float*)d_in[0];
  const float* resid      = (const float*)d_in[1];
  const float* stop_resid = (const float*)d_in[2];
  const void*  validp     = d_in[3];
  const int*   batch      = (const int*)d_in[4];
  const int E = in_sizes[0];
  const int G = in_sizes[2];

  int* flag = (int*)d_ws;            // ws[0]: valid_edges format flag
  int* ptr  = (int*)d_ws + 64;       // ws[64..64+G+1): segment pointers
  float* out = (float*)d_out;

  int sample_bytes = (E < 262144) ? (E & ~3) : 262144;  // safe under byte interp
  gfn_detect<<<1, BLOCK, 0, stream>>>((const unsigned int*)validp,
                                      sample_bytes / 4, sample_bytes, flag);
  gfn_ptr<<<(G + 1 + BLOCK - 1) / BLOCK, BLOCK, 0, stream>>>(batch, E, G, ptr);
  gfn_main<<<G, BLOCK, 0, stream>>>(scores, resid, stop_resid, validp, ptr,
                                    flag, out, E, G);
}

// Round 2
// 47.228 us; speedup vs baseline: 1.8989x; 1.8989x over previous
//
#include <hip/hip_runtime.h>
#include <hip/hip_bf16.h>
#include <math.h>
#include <climits>

#define BLOCK 256
#define CAP 4992                 // LDS floats per block: 19968 B -> 8 blocks/CU
#define LARGE_NEG (-1.0e9f)
#define SCORE_EPS 1e-6f
#define RANDP 0.1f
#define PROB_EPS 1e-12f
#define F32EPS 1.1920928955078125e-7f   // torch.finfo(float32).eps

// ---------- block reduction helpers (256 threads = 4 waves of 64) ----------
__device__ __forceinline__ float block_max_f(float v, float* redf) {
#pragma unroll
  for (int o = 32; o >= 1; o >>= 1) v = fmaxf(v, __shfl_xor(v, o));
  if ((threadIdx.x & 63) == 0) redf[threadIdx.x >> 6] = v;
  __syncthreads();
  float r = fmaxf(fmaxf(redf[0], redf[1]), fmaxf(redf[2], redf[3]));
  __syncthreads();
  return r;
}

__device__ __forceinline__ float block_sum_f(float v, float* redf) {
#pragma unroll
  for (int o = 32; o >= 1; o >>= 1) v += __shfl_xor(v, o);
  if ((threadIdx.x & 63) == 0) redf[threadIdx.x >> 6] = v;
  __syncthreads();
  float r = (redf[0] + redf[1]) + (redf[2] + redf[3]);
  __syncthreads();
  return r;
}

// ---------- kernel 1: fused setup ------------------------------------------
// Blocks [0, nbPtr): segment pointers via binary search (edge_batch sorted).
// Block nbPtr: valid_edges storage-format detect on a small sample.
//   byte-bool (~90% nonzero bytes) vs int32 0/1 (~22.5%) vs f32 0/1 (~45%).
//   flag=1 -> 1 byte/elem; flag=0 -> 4 bytes/elem (word-nonzero test is
//   correct for both int 0/1 and float 0.0/1.0).
__global__ void gfn_setup(const int* __restrict__ batch, int E, int G,
                          int* __restrict__ ptr,
                          const unsigned int* __restrict__ vwords, int nwords,
                          int nbytes, int* __restrict__ flag, int nbPtr) {
  if ((int)blockIdx.x < nbPtr) {
    int g = blockIdx.x * BLOCK + threadIdx.x;
    if (g > G) return;
    int lo = 0, hi = E;
    while (lo < hi) {
      int mid = (lo + hi) >> 1;
      if (batch[mid] < g) lo = mid + 1; else hi = mid;
    }
    ptr[g] = lo;   // first edge with batch >= g; segment g = [ptr[g], ptr[g+1])
  } else {
    int c = 0;
    for (int i = threadIdx.x; i < nwords; i += BLOCK) {
      unsigned int w = vwords[i];
      c += ((w & 0x000000FFu) != 0) + ((w & 0x0000FF00u) != 0) +
           ((w & 0x00FF0000u) != 0) + ((w & 0xFF000000u) != 0);
    }
#pragma unroll
    for (int o = 32; o >= 1; o >>= 1) c += __shfl_xor(c, o);
    __shared__ int part[4];
    if ((threadIdx.x & 63) == 0) part[threadIdx.x >> 6] = c;
    __syncthreads();
    if (threadIdx.x == 0) {
      int t = part[0] + part[1] + part[2] + part[3];
      flag[0] = (2 * t > nbytes) ? 1 : 0;
    }
  }
}

// ---------- kernel 2: one workgroup per graph, full fused pipeline --------
__global__ void gfn_main(const float* __restrict__ scores,
                         const float* __restrict__ resid,
                         const float* __restrict__ stop_resid,
                         const void* __restrict__ validp,
                         const int* __restrict__ ptr,
                         const int* __restrict__ flag,
                         float* __restrict__ out, int E, int G) {
  __shared__ float sdata[CAP];
  __shared__ float redf[4];
  __shared__ int redi[4];

  const int g = blockIdx.x;
  const int start = ptr[g];
  const int end = ptr[g + 1];
  const int n = end - start;
  const bool useLds = (n <= CAP);          // always true for this data; safe fallback otherwise
  const bool byteFmt = (flag[0] != 0);
  const unsigned char* vb = (const unsigned char*)validp;
  const int* vi = (const int*)validp;

  auto load_l = [&](int e) -> float {      // masked base logit
    float s = scores[e];
    int v = byteFmt ? (int)vb[e] : vi[e];
    return v ? __logf(fmaxf(s, SCORE_EPS)) : LARGE_NEG;
  };

  // ---- stage 1: base distribution (stop logit = 0, temp = 1) ----
  float m1 = LARGE_NEG, vc = 0.f;
  for (int i = threadIdx.x; i < n; i += BLOCK) {
    float l = load_l(start + i);
    if (useLds) sdata[i] = l;
    m1 = fmaxf(m1, l);
    if (l != LARGE_NEG) vc += 1.f;         // valid count
  }
  m1 = block_max_f(m1, redf);              // == LARGE_NEG if n==0 or none valid (matches ref)
  vc = block_sum_f(vc, redf);
  const float mj1 = fmaxf(m1, 0.f);
  float s1 = 0.f;
  for (int i = threadIdx.x; i < n; i += BLOCK) {
    float l = useLds ? sdata[i] : load_l(start + i);
    s1 += __expf(l - mj1);                 // invalid: exp(-1e9 - mj) == 0 exactly
  }
  s1 = block_sum_f(s1, redf);
  const float ld1 = mj1 + __logf(s1 + __expf(-mj1) + F32EPS);

  // ---- stage 2: combined = base_log + residual, renormalize (temp = 1) ----
  float m2 = LARGE_NEG;
  for (int i = threadIdx.x; i < n; i += BLOCK) {
    float l = useLds ? sdata[i] : load_l(start + i);
    float r = resid[start + i];
    float c = (l != LARGE_NEG) ? (l - ld1 + r) : LARGE_NEG;
    if (useLds) sdata[i] = c;              // overwrite own slots
    m2 = fmaxf(m2, c);
  }
  m2 = block_max_f(m2, redf);
  const float ss2 = stop_resid[g] - ld1;   // (0 - ld1) + stop_residual
  const float mj2 = fmaxf(m2, ss2);
  float s2 = 0.f;
  for (int i = threadIdx.x; i < n; i += BLOCK) {
    float c;
    if (useLds) c = sdata[i];
    else {
      float l = load_l(start + i);
      c = (l != LARGE_NEG) ? (l - ld1 + resid[start + i]) : LARGE_NEG;
    }
    s2 += __expf(c - mj2);
  }
  s2 = block_sum_f(s2, redf);
  const float ld2 = mj2 + __logf(s2 + __expf(ss2 - mj2) + F32EPS);
  const float clean_stop = ss2 - ld2;
  const float total = fmaxf(vc + 1.f, 1.f);
  const float invt = 1.f / total;

  // ---- stage 3: write clean_log_edge, mixed-sample argmax, outputs ----
  float bv = -INFINITY;                    // jax segment_max identity
  int bi = INT_MAX;                        // jax segment_min identity
  for (int i = threadIdx.x; i < n; i += BLOCK) {
    int e = start + i;
    float c;
    if (useLds) c = sdata[i];
    else {
      float l = load_l(e);
      c = (l != LARGE_NEG) ? (l - ld1 + resid[e]) : LARGE_NEG;
    }
    bool v = (c != LARGE_NEG);
    float clean = c - ld2;
    out[e] = v ? clean : LARGE_NEG;        // output 0
    float ls;
    if (v) {
      float p = (1.f - RANDP) * __expf(clean) + RANDP * invt;
      ls = __logf(fmaxf(p, PROB_EPS));
    } else ls = LARGE_NEG;
    if (ls > bv || (ls == bv && e < bi)) { bv = ls; bi = e; }   // min idx on ties
  }
#pragma unroll
  for (int o = 32; o >= 1; o >>= 1) {
    float v2 = __shfl_xor(bv, o);
    int i2 = __shfl_xor(bi, o);
    if (v2 > bv || (v2 == bv && i2 < bi)) { bv = v2; bi = i2; }
  }
  if ((threadIdx.x & 63) == 0) { redf[threadIdx.x >> 6] = bv; redi[threadIdx.x >> 6] = bi; }
  __syncthreads();
  if (threadIdx.x == 0) {
    bv = redf[0]; bi = redi[0];
    for (int w = 1; w < 4; ++w) {
      float v2 = redf[w]; int i2 = redi[w];
      if (v2 > bv || (v2 == bv && i2 < bi)) { bv = v2; bi = i2; }
    }
    float ssp = (1.f - RANDP) * __expf(clean_stop) + RANDP * invt;
    float lss = __logf(fmaxf(ssp, PROB_EPS));
    bool take_stop = (lss >= bv);
    float action = take_stop ? (float)end : (float)bi;   // stop idx = ptr[g+1]
    float lpf;
    if (take_stop) {
      lpf = clean_stop;
    } else {
      // !take_stop => bi is a valid edge inside [start, end)
      int cb = bi < (E - 1) ? bi : (E - 1);
      float chosen;
      if (useLds) {
        chosen = sdata[cb - start] - ld2;
      } else {
        float l = load_l(cb);
        float c = (l != LARGE_NEG) ? (l - ld1 + resid[cb]) : LARGE_NEG;
        chosen = c - ld2;
      }
      lpf = chosen;
    }
    out[E + g]         = clean_stop;       // output 1
    out[E + G + g]     = action;           // output 2 (int stored as exact f32)
    out[E + 2 * G + g] = lpf;              // output 3
  }
}

extern "C" void kernel_launch(void* const* d_in, const int* in_sizes, int n_in,
                              void* d_out, int out_size, void* d_ws, size_t ws_size,
                              hipStream_t stream) {
  const float* scores     = (const float*)d_in[0];
  const float* resid      = (const float*)d_in[1];
  const float* stop_resid = (const float*)d_in[2];
  const void*  validp     = d_in[3];
  const int*   batch      = (const int*)d_in[4];
  const int E = in_sizes[0];
  const int G = in_sizes[2];

  int* flag = (int*)d_ws;            // ws[0]: valid_edges format flag
  int* ptr  = (int*)d_ws + 64;       // ws[64..64+G+1): segment pointers
  float* out = (float*)d_out;

  // 8 KB sample: nonzero-byte fraction separates byte-bool (90%) from
  // int32 (22.5%) / f32 (45%) with sigma < 0.6%.
  int sample_bytes = (E < 8192) ? (E & ~3) : 8192;
  int nbPtr = (G + 1 + BLOCK - 1) / BLOCK;
  gfn_setup<<<nbPtr + 1, BLOCK, 0, stream>>>(batch, E, G, ptr,
                                             (const unsigned int*)validp,
                                             sample_bytes / 4, sample_bytes,
                                             flag, nbPtr);
  gfn_main<<<G, BLOCK, 0, stream>>>(scores, resid, stop_resid, validp, ptr,
                                    flag, out, E, G);
}

// Round 3
// 42.528 us; speedup vs baseline: 2.1088x; 1.1105x over previous
//
#include <hip/hip_runtime.h>
#include <math.h>
#include <climits>

#define BLOCK 256
#define NCHUNK 5
#define REGCAP (NCHUNK * BLOCK * 4)     // 5120 aligned elements per block
#define LARGE_NEG (-1.0e9f)
#define SCORE_EPS 1e-6f
#define RANDP 0.1f
#define PROB_EPS 1e-12f
#define F32EPS 1.1920928955078125e-7f   // torch.finfo(float32).eps

// ---------- kernel 1: fused setup ------------------------------------------
// Blocks [0, nbPtr): segment pointers via binary search (edge_batch sorted).
// Block nbPtr: valid_edges storage-format detect on an 8 KB sample.
//   byte-bool (~90% nonzero bytes) vs int32 0/1 (~22.5%) vs f32 0/1 (~45%).
//   flag=1 -> 1 byte/elem; flag=0 -> 4 bytes/elem.
__global__ void gfn_setup(const int* __restrict__ batch, int E, int G,
                          int* __restrict__ ptr,
                          const unsigned int* __restrict__ vwords, int nwords,
                          int nbytes, int* __restrict__ flag, int nbPtr) {
  if ((int)blockIdx.x < nbPtr) {
    int g = blockIdx.x * BLOCK + threadIdx.x;
    if (g > G) return;
    int lo = 0, hi = E;
    while (lo < hi) {
      int mid = (lo + hi) >> 1;
      if (batch[mid] < g) lo = mid + 1; else hi = mid;
    }
    ptr[g] = lo;   // first edge with batch >= g; segment g = [ptr[g], ptr[g+1])
  } else {
    int c = 0;
    for (int i = threadIdx.x; i < nwords; i += BLOCK) {
      unsigned int w = vwords[i];
      c += ((w & 0x000000FFu) != 0) + ((w & 0x0000FF00u) != 0) +
           ((w & 0x00FF0000u) != 0) + ((w & 0xFF000000u) != 0);
    }
#pragma unroll
    for (int o = 32; o >= 1; o >>= 1) c += __shfl_xor(c, o);
    __shared__ int part[4];
    if ((threadIdx.x & 63) == 0) part[threadIdx.x >> 6] = c;
    __syncthreads();
    if (threadIdx.x == 0) {
      int t = part[0] + part[1] + part[2] + part[3];
      flag[0] = (2 * t > nbytes) ? 1 : 0;
    }
  }
}

// ---------- kernel 2: one workgroup per graph, register-resident pipeline --
__global__ __launch_bounds__(BLOCK) void
gfn_main(const float* __restrict__ scores,
         const float* __restrict__ resid,
         const float* __restrict__ stop_resid,
         const void* __restrict__ validp,
         const int* __restrict__ ptr,
         const int* __restrict__ flag,
         float* __restrict__ out, int E, int G) {
  __shared__ float redf[8];
  __shared__ int redi[4];

  const int g = blockIdx.x;
  const int start = ptr[g];
  const int end = ptr[g + 1];
  const bool byteFmt = (flag[0] != 0);
  const unsigned char* vb = (const unsigned char*)validp;
  const int* vi = (const int*)validp;
  const int abase = start & ~3;          // 16B-aligned segment base

  if ((E & 3) == 0 && (end - abase) <= REGCAP) {
    // =================== fast path: values live in registers ===============
    float c[NCHUNK][4];
    const int t4 = (int)threadIdx.x * 4;

    // ---- pass 1: scores+valid -> base logits in regs; online max + count --
    float m1 = LARGE_NEG, vc = 0.f;
#pragma unroll
    for (int j = 0; j < NCHUNK; ++j) {
      const int e0 = abase + j * (BLOCK * 4) + t4;
      if (e0 < end) {   // e0 % 4 == 0 and E % 4 == 0 -> e0+3 <= E-1 (safe)
        const float4 s4 = *(const float4*)(scores + e0);
        int vv[4];
        if (byteFmt) {
          const uchar4 u = *(const uchar4*)(vb + e0);
          vv[0] = u.x; vv[1] = u.y; vv[2] = u.z; vv[3] = u.w;
        } else {
          const int4 u = *(const int4*)(vi + e0);
          vv[0] = u.x; vv[1] = u.y; vv[2] = u.z; vv[3] = u.w;
        }
        const float ss[4] = {s4.x, s4.y, s4.z, s4.w};
#pragma unroll
        for (int k = 0; k < 4; ++k) {
          const int e = e0 + k;
          const bool ok = (e >= start) & (e < end) & (vv[k] != 0);
          const float l = ok ? __logf(fmaxf(ss[k], SCORE_EPS)) : LARGE_NEG;
          c[j][k] = l;                       // out-of-range -> LARGE_NEG (inert)
          m1 = fmaxf(m1, l);
          vc += ok ? 1.f : 0.f;
        }
      } else {
#pragma unroll
        for (int k = 0; k < 4; ++k) c[j][k] = LARGE_NEG;
      }
    }
    // fused block reduce: max(m1), sum(vc) — one barrier round
#pragma unroll
    for (int o = 32; o >= 1; o >>= 1) {
      m1 = fmaxf(m1, __shfl_xor(m1, o));
      vc += __shfl_xor(vc, o);
    }
    if ((threadIdx.x & 63) == 0) {
      const int w = threadIdx.x >> 6;
      redf[w] = m1; redf[4 + w] = vc;
    }
    __syncthreads();
    m1 = fmaxf(fmaxf(redf[0], redf[1]), fmaxf(redf[2], redf[3]));
    vc = (redf[4] + redf[5]) + (redf[6] + redf[7]);
    __syncthreads();

    // ---- pass 2 (regs only): sum exp for base denom -----------------------
    const float mj1 = fmaxf(m1, 0.f);
    float s1 = 0.f;
#pragma unroll
    for (int j = 0; j < NCHUNK; ++j)
#pragma unroll
      for (int k = 0; k < 4; ++k) s1 += __expf(c[j][k] - mj1);  // inert: exp->0
#pragma unroll
    for (int o = 32; o >= 1; o >>= 1) s1 += __shfl_xor(s1, o);
    if ((threadIdx.x & 63) == 0) redf[threadIdx.x >> 6] = s1;
    __syncthreads();
    s1 = (redf[0] + redf[1]) + (redf[2] + redf[3]);
    __syncthreads();
    const float ld1 = mj1 + __logf(s1 + __expf(-mj1) + F32EPS);

    // ---- pass 3: + residual, renormalize at temp=1 ------------------------
    float m2 = LARGE_NEG;
#pragma unroll
    for (int j = 0; j < NCHUNK; ++j) {
      const int e0 = abase + j * (BLOCK * 4) + t4;
      if (e0 < end) {
        const float4 r4 = *(const float4*)(resid + e0);
        const float rr[4] = {r4.x, r4.y, r4.z, r4.w};
#pragma unroll
        for (int k = 0; k < 4; ++k) {
          const float l = c[j][k];
          const float cc = (l != LARGE_NEG) ? (l - ld1 + rr[k]) : LARGE_NEG;
          c[j][k] = cc;
          m2 = fmaxf(m2, cc);
        }
      }
    }
#pragma unroll
    for (int o = 32; o >= 1; o >>= 1) m2 = fmaxf(m2, __shfl_xor(m2, o));
    if ((threadIdx.x & 63) == 0) redf[threadIdx.x >> 6] = m2;
    __syncthreads();
    m2 = fmaxf(fmaxf(redf[0], redf[1]), fmaxf(redf[2], redf[3]));
    __syncthreads();

    const float ss2 = stop_resid[g] - ld1;   // (0 - ld1) + stop_residual
    const float mj2 = fmaxf(m2, ss2);

    // ---- pass 4 (regs only): sum exp for combined denom -------------------
    float s2 = 0.f;
#pragma unroll
    for (int j = 0; j < NCHUNK; ++j)
#pragma unroll
      for (int k = 0; k < 4; ++k) s2 += __expf(c[j][k] - mj2);
#pragma unroll
    for (int o = 32; o >= 1; o >>= 1) s2 += __shfl_xor(s2, o);
    if ((threadIdx.x & 63) == 0) redf[threadIdx.x >> 6] = s2;
    __syncthreads();
    s2 = (redf[0] + redf[1]) + (redf[2] + redf[3]);
    __syncthreads();
    const float ld2 = mj2 + __logf(s2 + __expf(ss2 - mj2) + F32EPS);
    const float clean_stop = ss2 - ld2;
    const float invt = 1.f / fmaxf(vc + 1.f, 1.f);

    // ---- pass 5: write clean_log_edge (float4 interior), mixed argmax -----
    float bv = -INFINITY;                  // jax segment_max identity
    int bi = INT_MAX;                      // jax segment_min identity
    float bc = 0.f;                        // winner's clean_log_edge
#pragma unroll
    for (int j = 0; j < NCHUNK; ++j) {
      const int e0 = abase + j * (BLOCK * 4) + t4;
      if (e0 < end) {
        float ov[4];
#pragma unroll
        for (int k = 0; k < 4; ++k) {
          const int e = e0 + k;
          const float cc = c[j][k];
          const bool v = (cc != LARGE_NEG);
          const float clean = cc - ld2;
          ov[k] = v ? clean : LARGE_NEG;
          if ((e >= start) & (e < end)) {
            float ls;
            if (v) {
              const float p = (1.f - RANDP) * __expf(clean) + RANDP * invt;
              ls = __logf(fmaxf(p, PROB_EPS));
            } else ls = LARGE_NEG;
            if (ls > bv || (ls == bv && e < bi)) { bv = ls; bi = e; bc = clean; }
          }
        }
        if (e0 >= start && e0 + 4 <= end) {
          *(float4*)(out + e0) = make_float4(ov[0], ov[1], ov[2], ov[3]);
        } else {
#pragma unroll
          for (int k = 0; k < 4; ++k) {
            const int e = e0 + k;
            if (e >= start && e < end) out[e] = ov[k];
          }
        }
      }
    }
    // block argmax with (val, idx, clean) triple
#pragma unroll
    for (int o = 32; o >= 1; o >>= 1) {
      const float v2 = __shfl_xor(bv, o);
      const int i2 = __shfl_xor(bi, o);
      const float c2 = __shfl_xor(bc, o);
      if (v2 > bv || (v2 == bv && i2 < bi)) { bv = v2; bi = i2; bc = c2; }
    }
    if ((threadIdx.x & 63) == 0) {
      const int w = threadIdx.x >> 6;
      redf[w] = bv; redf[4 + w] = bc; redi[w] = bi;
    }
    __syncthreads();
    if (threadIdx.x == 0) {
      bv = redf[0]; bi = redi[0]; bc = redf[4];
      for (int w = 1; w < 4; ++w) {
        if (redf[w] > bv || (redf[w] == bv && redi[w] < bi)) {
          bv = redf[w]; bi = redi[w]; bc = redf[4 + w];
        }
      }
      const float ssp = (1.f - RANDP) * __expf(clean_stop) + RANDP * invt;
      const float lss = __logf(fmaxf(ssp, PROB_EPS));
      const bool take_stop = (lss >= bv);   // !take_stop => valid edge won => bc correct
      out[E + g]         = clean_stop;                       // output 1
      out[E + G + g]     = take_stop ? (float)end : (float)bi; // output 2
      out[E + 2 * G + g] = take_stop ? clean_stop : bc;      // output 3
    }
    return;
  }

  // =================== fallback: 5-pass global reread (n > REGCAP) =========
  const int n = end - start;
  auto load_l = [&](int e) -> float {
    float s = scores[e];
    int v = byteFmt ? (int)vb[e] : vi[e];
    return v ? __logf(fmaxf(s, SCORE_EPS)) : LARGE_NEG;
  };

  float m1 = LARGE_NEG, vc = 0.f;
  for (int i = threadIdx.x; i < n; i += BLOCK) {
    float l = load_l(start + i);
    m1 = fmaxf(m1, l);
    if (l != LARGE_NEG) vc += 1.f;
  }
#pragma unroll
  for (int o = 32; o >= 1; o >>= 1) {
    m1 = fmaxf(m1, __shfl_xor(m1, o));
    vc += __shfl_xor(vc, o);
  }
  if ((threadIdx.x & 63) == 0) {
    const int w = threadIdx.x >> 6;
    redf[w] = m1; redf[4 + w] = vc;
  }
  __syncthreads();
  m1 = fmaxf(fmaxf(redf[0], redf[1]), fmaxf(redf[2], redf[3]));
  vc = (redf[4] + redf[5]) + (redf[6] + redf[7]);
  __syncthreads();

  const float mj1 = fmaxf(m1, 0.f);
  float s1 = 0.f;
  for (int i = threadIdx.x; i < n; i += BLOCK)
    s1 += __expf(load_l(start + i) - mj1);
#pragma unroll
  for (int o = 32; o >= 1; o >>= 1) s1 += __shfl_xor(s1, o);
  if ((threadIdx.x & 63) == 0) redf[threadIdx.x >> 6] = s1;
  __syncthreads();
  s1 = (redf[0] + redf[1]) + (redf[2] + redf[3]);
  __syncthreads();
  const float ld1 = mj1 + __logf(s1 + __expf(-mj1) + F32EPS);

  float m2 = LARGE_NEG;
  for (int i = threadIdx.x; i < n; i += BLOCK) {
    float l = load_l(start + i);
    float cc = (l != LARGE_NEG) ? (l - ld1 + resid[start + i]) : LARGE_NEG;
    m2 = fmaxf(m2, cc);
  }
#pragma unroll
  for (int o = 32; o >= 1; o >>= 1) m2 = fmaxf(m2, __shfl_xor(m2, o));
  if ((threadIdx.x & 63) == 0) redf[threadIdx.x >> 6] = m2;
  __syncthreads();
  m2 = fmaxf(fmaxf(redf[0], redf[1]), fmaxf(redf[2], redf[3]));
  __syncthreads();

  const float ss2 = stop_resid[g] - ld1;
  const float mj2 = fmaxf(m2, ss2);
  float s2 = 0.f;
  for (int i = threadIdx.x; i < n; i += BLOCK) {
    float l = load_l(start + i);
    float cc = (l != LARGE_NEG) ? (l - ld1 + resid[start + i]) : LARGE_NEG;
    s2 += __expf(cc - mj2);
  }
#pragma unroll
  for (int o = 32; o >= 1; o >>= 1) s2 += __shfl_xor(s2, o);
  if ((threadIdx.x & 63) == 0) redf[threadIdx.x >> 6] = s2;
  __syncthreads();
  s2 = (redf[0] + redf[1]) + (redf[2] + redf[3]);
  __syncthreads();
  const float ld2 = mj2 + __logf(s2 + __expf(ss2 - mj2) + F32EPS);
  const float clean_stop = ss2 - ld2;
  const float invt = 1.f / fmaxf(vc + 1.f, 1.f);

  float bv = -INFINITY; int bi = INT_MAX; float bc = 0.f;
  for (int i = threadIdx.x; i < n; i += BLOCK) {
    const int e = start + i;
    float l = load_l(e);
    float cc = (l != LARGE_NEG) ? (l - ld1 + resid[e]) : LARGE_NEG;
    const bool v = (cc != LARGE_NEG);
    const float clean = cc - ld2;
    out[e] = v ? clean : LARGE_NEG;
    float ls;
    if (v) {
      const float p = (1.f - RANDP) * __expf(clean) + RANDP * invt;
      ls = __logf(fmaxf(p, PROB_EPS));
    } else ls = LARGE_NEG;
    if (ls > bv || (ls == bv && e < bi)) { bv = ls; bi = e; bc = clean; }
  }
#pragma unroll
  for (int o = 32; o >= 1; o >>= 1) {
    const float v2 = __shfl_xor(bv, o);
    const int i2 = __shfl_xor(bi, o);
    const float c2 = __shfl_xor(bc, o);
    if (v2 > bv || (v2 == bv && i2 < bi)) { bv = v2; bi = i2; bc = c2; }
  }
  if ((threadIdx.x & 63) == 0) {
    const int w = threadIdx.x >> 6;
    redf[w] = bv; redf[4 + w] = bc; redi[w] = bi;
  }
  __syncthreads();
  if (threadIdx.x == 0) {
    bv = redf[0]; bi = redi[0]; bc = redf[4];
    for (int w = 1; w < 4; ++w) {
      if (redf[w] > bv || (redf[w] == bv && redi[w] < bi)) {
        bv = redf[w]; bi = redi[w]; bc = redf[4 + w];
      }
    }
    const float ssp = (1.f - RANDP) * __expf(clean_stop) + RANDP * invt;
    const float lss = __logf(fmaxf(ssp, PROB_EPS));
    const bool take_stop = (lss >= bv);
    out[E + g]         = clean_stop;
    out[E + G + g]     = take_stop ? (float)end : (float)bi;
    out[E + 2 * G + g] = take_stop ? clean_stop : bc;
  }
}

extern "C" void kernel_launch(void* const* d_in, const int* in_sizes, int n_in,
                              void* d_out, int out_size, void* d_ws, size_t ws_size,
                              hipStream_t stream) {
  const float* scores     = (const float*)d_in[0];
  const float* resid      = (const float*)d_in[1];
  const float* stop_resid = (const float*)d_in[2];
  const void*  validp     = d_in[3];
  const int*   batch      = (const int*)d_in[4];
  const int E = in_sizes[0];
  const int G = in_sizes[2];

  int* flag = (int*)d_ws;            // ws[0]: valid_edges format flag
  int* ptr  = (int*)d_ws + 64;       // ws[64..64+G+1): segment pointers
  float* out = (float*)d_out;

  int sample_bytes = (E < 8192) ? (E & ~3) : 8192;
  int nbPtr = (G + 1 + BLOCK - 1) / BLOCK;
  gfn_setup<<<nbPtr + 1, BLOCK, 0, stream>>>(batch, E, G, ptr,
                                             (const unsigned int*)validp,
                                             sample_bytes / 4, sample_bytes,
                                             flag, nbPtr);
  gfn_main<<<G, BLOCK, 0, stream>>>(scores, resid, stop_resid, validp, ptr,
                                    flag, out, E, G);
}

// Round 4
// 37.637 us; speedup vs baseline: 2.3829x; 1.1300x over previous
//
#include <hip/hip_runtime.h>
#include <math.h>
#include <climits>

#define BLOCK 256
#define NCHUNK 5
#define REGCAP (NCHUNK * BLOCK * 4)     // 5120 aligned elements per block
#define LARGE_NEG (-1.0e9f)
#define SCORE_EPS 1e-6f
#define RANDP 0.1f
#define PROB_EPS 1e-12f
#define F32EPS 1.1920928955078125e-7f   // torch.finfo(float32).eps

// ---------- kernel 1: fused setup ------------------------------------------
// Blocks [0, nbPtr): segment pointers via binary search (edge_batch sorted).
// Block nbPtr: valid_edges storage-format detect on an 8 KB sample.
//   byte-bool (~90% nonzero bytes) vs int32 0/1 (~22.5%) vs f32 0/1 (~45%).
//   flag=1 -> 1 byte/elem; flag=0 -> 4 bytes/elem.
__global__ void gfn_setup(const int* __restrict__ batch, int E, int G,
                          int* __restrict__ ptr,
                          const unsigned int* __restrict__ vwords, int nwords,
                          int nbytes, int* __restrict__ flag, int nbPtr) {
  if ((int)blockIdx.x < nbPtr) {
    int g = blockIdx.x * BLOCK + threadIdx.x;
    if (g > G) return;
    int lo = 0, hi = E;
    while (lo < hi) {
      int mid = (lo + hi) >> 1;
      if (batch[mid] < g) lo = mid + 1; else hi = mid;
    }
    ptr[g] = lo;   // first edge with batch >= g; segment g = [ptr[g], ptr[g+1])
  } else {
    int c = 0;
    for (int i = threadIdx.x; i < nwords; i += BLOCK) {
      unsigned int w = vwords[i];
      c += ((w & 0x000000FFu) != 0) + ((w & 0x0000FF00u) != 0) +
           ((w & 0x00FF0000u) != 0) + ((w & 0xFF000000u) != 0);
    }
#pragma unroll
    for (int o = 32; o >= 1; o >>= 1) c += __shfl_xor(c, o);
    __shared__ int part[4];
    if ((threadIdx.x & 63) == 0) part[threadIdx.x >> 6] = c;
    __syncthreads();
    if (threadIdx.x == 0) {
      int t = part[0] + part[1] + part[2] + part[3];
      flag[0] = (2 * t > nbytes) ? 1 : 0;
    }
  }
}

// ---------- kernel 2: one workgroup per graph, register-resident pipeline --
// Transcendental-minimized:
//   stage 1: exp(log(w)-mj1) == w/M with M = max(smax,1)  -> NO per-elem log/exp
//   stage 3: argmax(log_sample) == argmax(combined logit)  -> NO per-elem exp/log
// Irreducible per-element transcendentals: 1 log (combined logit, also the
// output) + 1 exp (stage-2 denominator).
__global__ __launch_bounds__(BLOCK) void
gfn_main(const float* __restrict__ scores,
         const float* __restrict__ resid,
         const float* __restrict__ stop_resid,
         const void* __restrict__ validp,
         const int* __restrict__ ptr,
         const int* __restrict__ flag,
         float* __restrict__ out, int E, int G) {
  __shared__ float redf[12];
  __shared__ int redi[4];

  const int g = blockIdx.x;
  const int start = ptr[g];
  const int end = ptr[g + 1];
  const bool byteFmt = (flag[0] != 0);
  const unsigned char* vb = (const unsigned char*)validp;
  const int* vi = (const int*)validp;
  const int abase = start & ~3;          // 16B-aligned segment base

  if ((E & 3) == 0 && (end - abase) <= REGCAP) {
    // =================== fast path: values live in registers ===============
    float c[NCHUNK][4];                  // masked score w, later combined logit
    const int t4 = (int)threadIdx.x * 4;

    // ---- pass A: scores+valid -> w = valid ? max(s,eps) : 0 ---------------
    //      fused reduce: smax (max), ssum (sum), vc (count). 0 transcendentals.
    float smax = 0.f, ssum = 0.f, vc = 0.f;
#pragma unroll
    for (int j = 0; j < NCHUNK; ++j) {
      const int e0 = abase + j * (BLOCK * 4) + t4;
      if (e0 < end) {   // e0 % 4 == 0 and E % 4 == 0 -> e0+3 <= E-1 (safe)
        const float4 s4 = *(const float4*)(scores + e0);
        int vv[4];
        if (byteFmt) {
          const uchar4 u = *(const uchar4*)(vb + e0);
          vv[0] = u.x; vv[1] = u.y; vv[2] = u.z; vv[3] = u.w;
        } else {
          const int4 u = *(const int4*)(vi + e0);
          vv[0] = u.x; vv[1] = u.y; vv[2] = u.z; vv[3] = u.w;
        }
        const float ss[4] = {s4.x, s4.y, s4.z, s4.w};
#pragma unroll
        for (int k = 0; k < 4; ++k) {
          const int e = e0 + k;
          const bool ok = (e >= start) & (e < end) & (vv[k] != 0);
          const float w = ok ? fmaxf(ss[k], SCORE_EPS) : 0.f;
          c[j][k] = w;
          smax = fmaxf(smax, w);
          ssum += w;
          vc += ok ? 1.f : 0.f;
        }
      } else {
#pragma unroll
        for (int k = 0; k < 4; ++k) c[j][k] = 0.f;
      }
    }
#pragma unroll
    for (int o = 32; o >= 1; o >>= 1) {
      smax = fmaxf(smax, __shfl_xor(smax, o));
      ssum += __shfl_xor(ssum, o);
      vc += __shfl_xor(vc, o);
    }
    if ((threadIdx.x & 63) == 0) {
      const int w = threadIdx.x >> 6;
      redf[w] = smax; redf[4 + w] = ssum; redf[8 + w] = vc;
    }
    __syncthreads();
    smax = fmaxf(fmaxf(redf[0], redf[1]), fmaxf(redf[2], redf[3]));
    ssum = (redf[4] + redf[5]) + (redf[6] + redf[7]);
    vc = (redf[8] + redf[9]) + (redf[10] + redf[11]);
    __syncthreads();

    // mj1 = max(log smax, 0) = log(max(smax,1)); exp_edges = ssum/M; exp_stop = 1/M
    const float M = fmaxf(smax, 1.f);
    const float invM = 1.f / M;
    const float ld1 = __logf(M) + __logf(ssum * invM + invM + F32EPS);

    // ---- pass B: + residual -> combined logit c; reduce m2 ----------------
    float m2 = LARGE_NEG;
#pragma unroll
    for (int j = 0; j < NCHUNK; ++j) {
      const int e0 = abase + j * (BLOCK * 4) + t4;
      if (e0 < end) {
        const float4 r4 = *(const float4*)(resid + e0);
        const float rr[4] = {r4.x, r4.y, r4.z, r4.w};
#pragma unroll
        for (int k = 0; k < 4; ++k) {
          const float w = c[j][k];
          const float cc = (w > 0.f) ? ((__logf(w) - ld1) + rr[k]) : LARGE_NEG;
          c[j][k] = cc;
          m2 = fmaxf(m2, cc);
        }
      } else {
#pragma unroll
        for (int k = 0; k < 4; ++k) c[j][k] = LARGE_NEG;
      }
    }
#pragma unroll
    for (int o = 32; o >= 1; o >>= 1) m2 = fmaxf(m2, __shfl_xor(m2, o));
    if ((threadIdx.x & 63) == 0) redf[threadIdx.x >> 6] = m2;
    __syncthreads();
    m2 = fmaxf(fmaxf(redf[0], redf[1]), fmaxf(redf[2], redf[3]));
    __syncthreads();

    const float ss2 = stop_resid[g] - ld1;   // (0 - ld1) + stop_residual
    const float mj2 = fmaxf(m2, ss2);

    // ---- pass C (regs only): stage-2 denominator --------------------------
    float s2 = 0.f;
#pragma unroll
    for (int j = 0; j < NCHUNK; ++j)
#pragma unroll
      for (int k = 0; k < 4; ++k) s2 += __expf(c[j][k] - mj2);  // inert -> 0
#pragma unroll
    for (int o = 32; o >= 1; o >>= 1) s2 += __shfl_xor(s2, o);
    if ((threadIdx.x & 63) == 0) redf[threadIdx.x >> 6] = s2;
    __syncthreads();
    s2 = (redf[0] + redf[1]) + (redf[2] + redf[3]);
    __syncthreads();
    const float ld2 = mj2 + __logf(s2 + __expf(ss2 - mj2) + F32EPS);
    const float clean_stop = ss2 - ld2;
    const float invt = 1.f / fmaxf(vc + 1.f, 1.f);

    // ---- pass D: write clean_log_edge; argmax by combined logit c ---------
    //      (p = 0.9*exp(c-ld2) + 0.1*invt is monotone in c, log is monotone
    //       -> argmax matches reference incl. min-index tie-break)
    float bv = -INFINITY;
    int bi = INT_MAX;
#pragma unroll
    for (int j = 0; j < NCHUNK; ++j) {
      const int e0 = abase + j * (BLOCK * 4) + t4;
      if (e0 < end) {
        float ov[4];
#pragma unroll
        for (int k = 0; k < 4; ++k) {
          const int e = e0 + k;
          const float cc = c[j][k];
          const bool v = (cc != LARGE_NEG);
          ov[k] = v ? (cc - ld2) : LARGE_NEG;
          if (v && (cc > bv || (cc == bv && e < bi))) { bv = cc; bi = e; }
        }
        if (e0 >= start && e0 + 4 <= end) {
          *(float4*)(out + e0) = make_float4(ov[0], ov[1], ov[2], ov[3]);
        } else {
#pragma unroll
          for (int k = 0; k < 4; ++k) {
            const int e = e0 + k;
            if (e >= start && e < end) out[e] = ov[k];
          }
        }
      }
    }
#pragma unroll
    for (int o = 32; o >= 1; o >>= 1) {
      const float v2 = __shfl_xor(bv, o);
      const int i2 = __shfl_xor(bi, o);
      if (v2 > bv || (v2 == bv && i2 < bi)) { bv = v2; bi = i2; }
    }
    if ((threadIdx.x & 63) == 0) {
      const int w = threadIdx.x >> 6;
      redf[w] = bv; redi[w] = bi;
    }
    __syncthreads();
    if (threadIdx.x == 0) {
      bv = redf[0]; bi = redi[0];
      for (int w = 1; w < 4; ++w) {
        if (redf[w] > bv || (redf[w] == bv && redi[w] < bi)) {
          bv = redf[w]; bi = redi[w];
        }
      }
      const bool anyvalid = (bi != INT_MAX);
      const float wclean = bv - ld2;       // winner's clean_log_edge
      float bvls = LARGE_NEG;              // best log_sample_edge (ref formula)
      if (anyvalid) {
        const float p = (1.f - RANDP) * __expf(wclean) + RANDP * invt;
        bvls = __logf(fmaxf(p, PROB_EPS));
      }
      const float ssp = (1.f - RANDP) * __expf(clean_stop) + RANDP * invt;
      const float lss = __logf(fmaxf(ssp, PROB_EPS));
      const bool take_stop = (lss >= bvls);
      out[E + g]         = clean_stop;                         // output 1
      out[E + G + g]     = take_stop ? (float)end : (float)bi; // output 2
      out[E + 2 * G + g] = take_stop ? clean_stop : wclean;    // output 3
    }
    return;
  }

  // =================== fallback: 5-pass global reread (n > REGCAP) =========
  const int n = end - start;
  auto load_l = [&](int e) -> float {
    float s = scores[e];
    int v = byteFmt ? (int)vb[e] : vi[e];
    return v ? __logf(fmaxf(s, SCORE_EPS)) : LARGE_NEG;
  };

  float m1 = LARGE_NEG, vc = 0.f;
  for (int i = threadIdx.x; i < n; i += BLOCK) {
    float l = load_l(start + i);
    m1 = fmaxf(m1, l);
    if (l != LARGE_NEG) vc += 1.f;
  }
#pragma unroll
  for (int o = 32; o >= 1; o >>= 1) {
    m1 = fmaxf(m1, __shfl_xor(m1, o));
    vc += __shfl_xor(vc, o);
  }
  if ((threadIdx.x & 63) == 0) {
    const int w = threadIdx.x >> 6;
    redf[w] = m1; redf[4 + w] = vc;
  }
  __syncthreads();
  m1 = fmaxf(fmaxf(redf[0], redf[1]), fmaxf(redf[2], redf[3]));
  vc = (redf[4] + redf[5]) + (redf[6] + redf[7]);
  __syncthreads();

  const float mj1 = fmaxf(m1, 0.f);
  float s1 = 0.f;
  for (int i = threadIdx.x; i < n; i += BLOCK)
    s1 += __expf(load_l(start + i) - mj1);
#pragma unroll
  for (int o = 32; o >= 1; o >>= 1) s1 += __shfl_xor(s1, o);
  if ((threadIdx.x & 63) == 0) redf[threadIdx.x >> 6] = s1;
  __syncthreads();
  s1 = (redf[0] + redf[1]) + (redf[2] + redf[3]);
  __syncthreads();
  const float ld1 = mj1 + __logf(s1 + __expf(-mj1) + F32EPS);

  float m2 = LARGE_NEG;
  for (int i = threadIdx.x; i < n; i += BLOCK) {
    float l = load_l(start + i);
    float cc = (l != LARGE_NEG) ? (l - ld1 + resid[start + i]) : LARGE_NEG;
    m2 = fmaxf(m2, cc);
  }
#pragma unroll
  for (int o = 32; o >= 1; o >>= 1) m2 = fmaxf(m2, __shfl_xor(m2, o));
  if ((threadIdx.x & 63) == 0) redf[threadIdx.x >> 6] = m2;
  __syncthreads();
  m2 = fmaxf(fmaxf(redf[0], redf[1]), fmaxf(redf[2], redf[3]));
  __syncthreads();

  const float ss2 = stop_resid[g] - ld1;
  const float mj2 = fmaxf(m2, ss2);
  float s2 = 0.f;
  for (int i = threadIdx.x; i < n; i += BLOCK) {
    float l = load_l(start + i);
    float cc = (l != LARGE_NEG) ? (l - ld1 + resid[start + i]) : LARGE_NEG;
    s2 += __expf(cc - mj2);
  }
#pragma unroll
  for (int o = 32; o >= 1; o >>= 1) s2 += __shfl_xor(s2, o);
  if ((threadIdx.x & 63) == 0) redf[threadIdx.x >> 6] = s2;
  __syncthreads();
  s2 = (redf[0] + redf[1]) + (redf[2] + redf[3]);
  __syncthreads();
  const float ld2 = mj2 + __logf(s2 + __expf(ss2 - mj2) + F32EPS);
  const float clean_stop = ss2 - ld2;
  const float invt = 1.f / fmaxf(vc + 1.f, 1.f);

  float bv = -INFINITY; int bi = INT_MAX; float bc = 0.f;
  for (int i = threadIdx.x; i < n; i += BLOCK) {
    const int e = start + i;
    float l = load_l(e);
    float cc = (l != LARGE_NEG) ? (l - ld1 + resid[e]) : LARGE_NEG;
    const bool v = (cc != LARGE_NEG);
    const float clean = cc - ld2;
    out[e] = v ? clean : LARGE_NEG;
    float ls;
    if (v) {
      const float p = (1.f - RANDP) * __expf(clean) + RANDP * invt;
      ls = __logf(fmaxf(p, PROB_EPS));
    } else ls = LARGE_NEG;
    if (ls > bv || (ls == bv && e < bi)) { bv = ls; bi = e; bc = clean; }
  }
#pragma unroll
  for (int o = 32; o >= 1; o >>= 1) {
    const float v2 = __shfl_xor(bv, o);
    const int i2 = __shfl_xor(bi, o);
    const float c2 = __shfl_xor(bc, o);
    if (v2 > bv || (v2 == bv && i2 < bi)) { bv = v2; bi = i2; bc = c2; }
  }
  if ((threadIdx.x & 63) == 0) {
    const int w = threadIdx.x >> 6;
    redf[w] = bv; redf[4 + w] = bc; redi[w] = bi;
  }
  __syncthreads();
  if (threadIdx.x == 0) {
    bv = redf[0]; bi = redi[0]; bc = redf[4];
    for (int w = 1; w < 4; ++w) {
      if (redf[w] > bv || (redf[w] == bv && redi[w] < bi)) {
        bv = redf[w]; bi = redi[w]; bc = redf[4 + w];
      }
    }
    const float ssp = (1.f - RANDP) * __expf(clean_stop) + RANDP * invt;
    const float lss = __logf(fmaxf(ssp, PROB_EPS));
    const bool take_stop = (lss >= bv);
    out[E + g]         = clean_stop;
    out[E + G + g]     = take_stop ? (float)end : (float)bi;
    out[E + 2 * G + g] = take_stop ? clean_stop : bc;
  }
}

extern "C" void kernel_launch(void* const* d_in, const int* in_sizes, int n_in,
                              void* d_out, int out_size, void* d_ws, size_t ws_size,
                              hipStream_t stream) {
  const float* scores     = (const float*)d_in[0];
  const float* resid      = (const float*)d_in[1];
  const float* stop_resid = (const float*)d_in[2];
  const void*  validp     = d_in[3];
  const int*   batch      = (const int*)d_in[4];
  const int E = in_sizes[0];
  const int G = in_sizes[2];

  int* flag = (int*)d_ws;            // ws[0]: valid_edges format flag
  int* ptr  = (int*)d_ws + 64;       // ws[64..64+G+1): segment pointers
  float* out = (float*)d_out;

  int sample_bytes = (E < 8192) ? (E & ~3) : 8192;
  int nbPtr = (G + 1 + BLOCK - 1) / BLOCK;
  gfn_setup<<<nbPtr + 1, BLOCK, 0, stream>>>(batch, E, G, ptr,
                                             (const unsigned int*)validp,
                                             sample_bytes / 4, sample_bytes,
                                             flag, nbPtr);
  gfn_main<<<G, BLOCK, 0, stream>>>(scores, resid, stop_resid, validp, ptr,
                                    flag, out, E, G);
}

// Round 5
// 37.146 us; speedup vs baseline: 2.4143x; 1.0132x over previous
//
#include <hip/hip_runtime.h>
#include <math.h>
#include <climits>

#define BLOCK 256
#define NCHUNK 5
#define REGCAP (NCHUNK * BLOCK * 4)     // 5120 aligned elements per block
#define LARGE_NEG (-1.0e9f)
#define SCORE_EPS 1e-6f
#define RANDP 0.1f
#define PROB_EPS 1e-12f
#define F32EPS 1.1920928955078125e-7f   // torch.finfo(float32).eps

typedef float f4v __attribute__((ext_vector_type(4)));

// ---------- kernel 1: fused setup ------------------------------------------
// Blocks [0, nbPtr): segment pointers via binary search (edge_batch sorted).
// Block nbPtr: valid_edges storage-format detect on an 8 KB sample.
//   byte-bool (~90% nonzero bytes) vs int32 0/1 (~22.5%) vs f32 0/1 (~45%).
//   flag=1 -> 1 byte/elem; flag=0 -> 4 bytes/elem.
__global__ void gfn_setup(const int* __restrict__ batch, int E, int G,
                          int* __restrict__ ptr,
                          const unsigned int* __restrict__ vwords, int nwords,
                          int nbytes, int* __restrict__ flag, int nbPtr) {
  if ((int)blockIdx.x < nbPtr) {
    int g = blockIdx.x * BLOCK + threadIdx.x;
    if (g > G) return;
    int lo = 0, hi = E;
    while (lo < hi) {
      int mid = (lo + hi) >> 1;
      if (batch[mid] < g) lo = mid + 1; else hi = mid;
    }
    ptr[g] = lo;   // first edge with batch >= g; segment g = [ptr[g], ptr[g+1])
  } else {
    int c = 0;
    for (int i = threadIdx.x; i < nwords; i += BLOCK) {
      unsigned int w = vwords[i];
      c += ((w & 0x000000FFu) != 0) + ((w & 0x0000FF00u) != 0) +
           ((w & 0x00FF0000u) != 0) + ((w & 0xFF000000u) != 0);
    }
#pragma unroll
    for (int o = 32; o >= 1; o >>= 1) c += __shfl_xor(c, o);
    __shared__ int part[4];
    if ((threadIdx.x & 63) == 0) part[threadIdx.x >> 6] = c;
    __syncthreads();
    if (threadIdx.x == 0) {
      int t = part[0] + part[1] + part[2] + part[3];
      flag[0] = (2 * t > nbytes) ? 1 : 0;
    }
  }
}

// ---------- kernel 2: one workgroup per graph, register-resident, 3-phase --
// Phase AB: single burst loading scores+valid+resid; t = log(w)+r in regs;
//           fused 4-tuple reduce (smax, ssum, vc, tmax).
//           Uses max((log w - ld1) + r) == max(log w + r) - ld1.
// Phase C : register-only exp-sum for stage-2 denominator.
// Phase D : nontemporal output writes + argmax by t (monotone equivalence).
__global__ __launch_bounds__(BLOCK) void
gfn_main(const float* __restrict__ scores,
         const float* __restrict__ resid,
         const float* __restrict__ stop_resid,
         const void* __restrict__ validp,
         const int* __restrict__ ptr,
         const int* __restrict__ flag,
         float* __restrict__ out, int E, int G) {
  __shared__ float redf[16];
  __shared__ int redi[4];

  const int g = blockIdx.x;
  const int start = ptr[g];
  const int end = ptr[g + 1];
  const bool byteFmt = (flag[0] != 0);
  const unsigned char* vb = (const unsigned char*)validp;
  const int* vi = (const int*)validp;
  const int abase = start & ~3;          // 16B-aligned segment base

  if ((E & 3) == 0 && (end - abase) <= REGCAP) {
    // =================== fast path: t lives in registers ===================
    float c[NCHUNK][4];                  // t = log(w) + r  (or LARGE_NEG)
    const int t4 = (int)threadIdx.x * 4;

    // ---- phase AB: one burst over all three inputs ------------------------
    float smax = 0.f, ssum = 0.f, vc = 0.f, tmax = LARGE_NEG;
#pragma unroll
    for (int j = 0; j < NCHUNK; ++j) {
      const int e0 = abase + j * (BLOCK * 4) + t4;
      if (e0 < end) {   // e0 % 4 == 0 and E % 4 == 0 -> e0+3 <= E-1 (safe)
        const float4 s4 = *(const float4*)(scores + e0);
        const float4 r4 = *(const float4*)(resid + e0);
        int vv[4];
        if (byteFmt) {
          const uchar4 u = *(const uchar4*)(vb + e0);
          vv[0] = u.x; vv[1] = u.y; vv[2] = u.z; vv[3] = u.w;
        } else {
          const int4 u = *(const int4*)(vi + e0);
          vv[0] = u.x; vv[1] = u.y; vv[2] = u.z; vv[3] = u.w;
        }
        const float ss[4] = {s4.x, s4.y, s4.z, s4.w};
        const float rr[4] = {r4.x, r4.y, r4.z, r4.w};
#pragma unroll
        for (int k = 0; k < 4; ++k) {
          const int e = e0 + k;
          const bool ok = (e >= start) & (e < end) & (vv[k] != 0);
          const float w = ok ? fmaxf(ss[k], SCORE_EPS) : 0.f;
          smax = fmaxf(smax, w);
          ssum += w;
          vc += ok ? 1.f : 0.f;
          const float t = ok ? (__logf(w) + rr[k]) : LARGE_NEG;
          c[j][k] = t;
          tmax = fmaxf(tmax, t);
        }
      } else {
#pragma unroll
        for (int k = 0; k < 4; ++k) c[j][k] = LARGE_NEG;
      }
    }
#pragma unroll
    for (int o = 32; o >= 1; o >>= 1) {
      smax = fmaxf(smax, __shfl_xor(smax, o));
      ssum += __shfl_xor(ssum, o);
      vc += __shfl_xor(vc, o);
      tmax = fmaxf(tmax, __shfl_xor(tmax, o));
    }
    if ((threadIdx.x & 63) == 0) {
      const int w = threadIdx.x >> 6;
      redf[w] = smax; redf[4 + w] = ssum; redf[8 + w] = vc; redf[12 + w] = tmax;
    }
    __syncthreads();
    smax = fmaxf(fmaxf(redf[0], redf[1]), fmaxf(redf[2], redf[3]));
    ssum = (redf[4] + redf[5]) + (redf[6] + redf[7]);
    vc = (redf[8] + redf[9]) + (redf[10] + redf[11]);
    tmax = fmaxf(fmaxf(redf[12], redf[13]), fmaxf(redf[14], redf[15]));
    __syncthreads();

    // ---- scalar stage-1/2 plumbing ----------------------------------------
    // mj1 = log(max(smax,1)); exp_edges = ssum/M; exp_stop = 1/M
    const float M = fmaxf(smax, 1.f);
    const float invM = 1.f / M;
    const float ld1 = __logf(M) + __logf(ssum * invM + invM + F32EPS);
    const float m2 = tmax - ld1;             // max combined edge logit
    const float ss2 = stop_resid[g] - ld1;   // combined stop logit
    const float mj2 = fmaxf(m2, ss2);
    const float off2 = ld1 + mj2;            // exp(c - mj2) = exp(t - off2)

    // ---- phase C (regs only): stage-2 denominator -------------------------
    float s2 = 0.f;
#pragma unroll
    for (int j = 0; j < NCHUNK; ++j)
#pragma unroll
      for (int k = 0; k < 4; ++k) s2 += __expf(c[j][k] - off2);  // inert -> 0
#pragma unroll
    for (int o = 32; o >= 1; o >>= 1) s2 += __shfl_xor(s2, o);
    if ((threadIdx.x & 63) == 0) redf[threadIdx.x >> 6] = s2;
    __syncthreads();
    s2 = (redf[0] + redf[1]) + (redf[2] + redf[3]);
    __syncthreads();
    const float ld2 = mj2 + __logf(s2 + __expf(ss2 - mj2) + F32EPS);
    const float clean_stop = ss2 - ld2;
    const float invt = 1.f / fmaxf(vc + 1.f, 1.f);
    const float off3 = ld1 + ld2;            // clean = t - off3

    // ---- phase D: NT writes; argmax by t (monotone => matches reference) --
    float bv = -INFINITY;
    int bi = INT_MAX;
#pragma unroll
    for (int j = 0; j < NCHUNK; ++j) {
      const int e0 = abase + j * (BLOCK * 4) + t4;
      if (e0 < end) {
        float ov[4];
#pragma unroll
        for (int k = 0; k < 4; ++k) {
          const int e = e0 + k;
          const float t = c[j][k];
          const bool v = (t != LARGE_NEG);
          ov[k] = v ? (t - off3) : LARGE_NEG;
          if (v && (t > bv || (t == bv && e < bi))) { bv = t; bi = e; }
        }
        if (e0 >= start && e0 + 4 <= end) {
          f4v val; val.x = ov[0]; val.y = ov[1]; val.z = ov[2]; val.w = ov[3];
          __builtin_nontemporal_store(val, (f4v*)(out + e0));
        } else {
#pragma unroll
          for (int k = 0; k < 4; ++k) {
            const int e = e0 + k;
            if (e >= start && e < end)
              __builtin_nontemporal_store(ov[k], out + e);
          }
        }
      }
    }
#pragma unroll
    for (int o = 32; o >= 1; o >>= 1) {
      const float v2 = __shfl_xor(bv, o);
      const int i2 = __shfl_xor(bi, o);
      if (v2 > bv || (v2 == bv && i2 < bi)) { bv = v2; bi = i2; }
    }
    if ((threadIdx.x & 63) == 0) {
      const int w = threadIdx.x >> 6;
      redf[w] = bv; redi[w] = bi;
    }
    __syncthreads();
    if (threadIdx.x == 0) {
      bv = redf[0]; bi = redi[0];
      for (int w = 1; w < 4; ++w) {
        if (redf[w] > bv || (redf[w] == bv && redi[w] < bi)) {
          bv = redf[w]; bi = redi[w];
        }
      }
      const bool anyvalid = (bi != INT_MAX);
      const float wclean = bv - off3;      // winner's clean_log_edge
      float bvls = LARGE_NEG;              // best log_sample_edge (ref formula)
      if (anyvalid) {
        const float p = (1.f - RANDP) * __expf(wclean) + RANDP * invt;
        bvls = __logf(fmaxf(p, PROB_EPS));
      }
      const float ssp = (1.f - RANDP) * __expf(clean_stop) + RANDP * invt;
      const float lss = __logf(fmaxf(ssp, PROB_EPS));
      const bool take_stop = (lss >= bvls);
      out[E + g]         = clean_stop;                         // output 1
      out[E + G + g]     = take_stop ? (float)end : (float)bi; // output 2
      out[E + 2 * G + g] = take_stop ? clean_stop : wclean;    // output 3
    }
    return;
  }

  // =================== fallback: 5-pass global reread (n > REGCAP) =========
  const int n = end - start;
  auto load_l = [&](int e) -> float {
    float s = scores[e];
    int v = byteFmt ? (int)vb[e] : vi[e];
    return v ? __logf(fmaxf(s, SCORE_EPS)) : LARGE_NEG;
  };

  float m1 = LARGE_NEG, vc = 0.f;
  for (int i = threadIdx.x; i < n; i += BLOCK) {
    float l = load_l(start + i);
    m1 = fmaxf(m1, l);
    if (l != LARGE_NEG) vc += 1.f;
  }
#pragma unroll
  for (int o = 32; o >= 1; o >>= 1) {
    m1 = fmaxf(m1, __shfl_xor(m1, o));
    vc += __shfl_xor(vc, o);
  }
  if ((threadIdx.x & 63) == 0) {
    const int w = threadIdx.x >> 6;
    redf[w] = m1; redf[4 + w] = vc;
  }
  __syncthreads();
  m1 = fmaxf(fmaxf(redf[0], redf[1]), fmaxf(redf[2], redf[3]));
  vc = (redf[4] + redf[5]) + (redf[6] + redf[7]);
  __syncthreads();

  const float mj1 = fmaxf(m1, 0.f);
  float s1 = 0.f;
  for (int i = threadIdx.x; i < n; i += BLOCK)
    s1 += __expf(load_l(start + i) - mj1);
#pragma unroll
  for (int o = 32; o >= 1; o >>= 1) s1 += __shfl_xor(s1, o);
  if ((threadIdx.x & 63) == 0) redf[threadIdx.x >> 6] = s1;
  __syncthreads();
  s1 = (redf[0] + redf[1]) + (redf[2] + redf[3]);
  __syncthreads();
  const float ld1 = mj1 + __logf(s1 + __expf(-mj1) + F32EPS);

  float m2 = LARGE_NEG;
  for (int i = threadIdx.x; i < n; i += BLOCK) {
    float l = load_l(start + i);
    float cc = (l != LARGE_NEG) ? (l - ld1 + resid[start + i]) : LARGE_NEG;
    m2 = fmaxf(m2, cc);
  }
#pragma unroll
  for (int o = 32; o >= 1; o >>= 1) m2 = fmaxf(m2, __shfl_xor(m2, o));
  if ((threadIdx.x & 63) == 0) redf[threadIdx.x >> 6] = m2;
  __syncthreads();
  m2 = fmaxf(fmaxf(redf[0], redf[1]), fmaxf(redf[2], redf[3]));
  __syncthreads();

  const float ss2 = stop_resid[g] - ld1;
  const float mj2 = fmaxf(m2, ss2);
  float s2 = 0.f;
  for (int i = threadIdx.x; i < n; i += BLOCK) {
    float l = load_l(start + i);
    float cc = (l != LARGE_NEG) ? (l - ld1 + resid[start + i]) : LARGE_NEG;
    s2 += __expf(cc - mj2);
  }
#pragma unroll
  for (int o = 32; o >= 1; o >>= 1) s2 += __shfl_xor(s2, o);
  if ((threadIdx.x & 63) == 0) redf[threadIdx.x >> 6] = s2;
  __syncthreads();
  s2 = (redf[0] + redf[1]) + (redf[2] + redf[3]);
  __syncthreads();
  const float ld2 = mj2 + __logf(s2 + __expf(ss2 - mj2) + F32EPS);
  const float clean_stop = ss2 - ld2;
  const float invt = 1.f / fmaxf(vc + 1.f, 1.f);

  float bv = -INFINITY; int bi = INT_MAX; float bc = 0.f;
  for (int i = threadIdx.x; i < n; i += BLOCK) {
    const int e = start + i;
    float l = load_l(e);
    float cc = (l != LARGE_NEG) ? (l - ld1 + resid[e]) : LARGE_NEG;
    const bool v = (cc != LARGE_NEG);
    const float clean = cc - ld2;
    out[e] = v ? clean : LARGE_NEG;
    float ls;
    if (v) {
      const float p = (1.f - RANDP) * __expf(clean) + RANDP * invt;
      ls = __logf(fmaxf(p, PROB_EPS));
    } else ls = LARGE_NEG;
    if (ls > bv || (ls == bv && e < bi)) { bv = ls; bi = e; bc = clean; }
  }
#pragma unroll
  for (int o = 32; o >= 1; o >>= 1) {
    const float v2 = __shfl_xor(bv, o);
    const int i2 = __shfl_xor(bi, o);
    const float c2 = __shfl_xor(bc, o);
    if (v2 > bv || (v2 == bv && i2 < bi)) { bv = v2; bi = i2; bc = c2; }
  }
  if ((threadIdx.x & 63) == 0) {
    const int w = threadIdx.x >> 6;
    redf[w] = bv; redf[4 + w] = bc; redi[w] = bi;
  }
  __syncthreads();
  if (threadIdx.x == 0) {
    bv = redf[0]; bi = redi[0]; bc = redf[4];
    for (int w = 1; w < 4; ++w) {
      if (redf[w] > bv || (redf[w] == bv && redi[w] < bi)) {
        bv = redf[w]; bi = redi[w]; bc = redf[4 + w];
      }
    }
    const float ssp = (1.f - RANDP) * __expf(clean_stop) + RANDP * invt;
    const float lss = __logf(fmaxf(ssp, PROB_EPS));
    const bool take_stop = (lss >= bv);
    out[E + g]         = clean_stop;
    out[E + G + g]     = take_stop ? (float)end : (float)bi;
    out[E + 2 * G + g] = take_stop ? clean_stop : bc;
  }
}

extern "C" void kernel_launch(void* const* d_in, const int* in_sizes, int n_in,
                              void* d_out, int out_size, void* d_ws, size_t ws_size,
                              hipStream_t stream) {
  const float* scores     = (const float*)d_in[0];
  const float* resid      = (const float*)d_in[1];
  const float* stop_resid = (const float*)d_in[2];
  const void*  validp     = d_in[3];
  const int*   batch      = (const int*)d_in[4];
  const int E = in_sizes[0];
  const int G = in_sizes[2];

  int* flag = (int*)d_ws;            // ws[0]: valid_edges format flag
  int* ptr  = (int*)d_ws + 64;       // ws[64..64+G+1): segment pointers
  float* out = (float*)d_out;

  int sample_bytes = (E < 8192) ? (E & ~3) : 8192;
  int nbPtr = (G + 1 + BLOCK - 1) / BLOCK;
  gfn_setup<<<nbPtr + 1, BLOCK, 0, stream>>>(batch, E, G, ptr,
                                             (const unsigned int*)validp,
                                             sample_bytes / 4, sample_bytes,
                                             flag, nbPtr);
  gfn_main<<<G, BLOCK, 0, stream>>>(scores, resid, stop_resid, validp, ptr,
                                    flag, out, E, G);
}